// Round 1
// baseline (331.975 us; speedup 1.0000x reference)
//
#include <hip/hip_runtime.h>
#include <stdint.h>
#include <math.h>

// RG-LRU: B=4, L=4096, D=1024.
//   r = sigmoid(x @ Wa^T + ba); i = sigmoid(x @ Wx^T + bx)
//   a_t = exp(8 * r * log(sigmoid(lmbd)));  b_t = sqrt(1-a_t^2) * i * x
//   h_t = a_t*h_{t-1} + b_t  (scan over L per (b,d) channel)
//
// Plan: convert x/W to bf16 -> one fused MFMA GEMM (N=2048 = [Wa;Wx]) whose
// epilogue writes a_t (cols<1024) and g=i*x (cols>=1024) -> 3-phase chunked
// scan (NC=32 chunks of CL=128) for parallelism over the sequential L dim.

#define D_DIM 1024
#define L_DIM 4096
#define B_DIM 4
#define M_DIM (B_DIM * L_DIM)   // 16384 rows
#define N_DIM (2 * D_DIM)       // 2048 (Wa cols then Wx cols)
#define K_DIM D_DIM             // 1024
#define NC 32
#define CL (L_DIM / NC)         // 128

typedef __attribute__((ext_vector_type(8))) short short8;
typedef __attribute__((ext_vector_type(4))) short short4v;
typedef __attribute__((ext_vector_type(4))) float float4v;

__device__ __forceinline__ unsigned short f2bf(float f) {
  unsigned u = __float_as_uint(f);
  u += 0x7fffu + ((u >> 16) & 1u);   // round-nearest-even
  return (unsigned short)(u >> 16);
}

__global__ void cvt_bf16(const float* __restrict__ in, short* __restrict__ out, int n4) {
  int i = blockIdx.x * blockDim.x + threadIdx.x;
  if (i >= n4) return;
  float4v v = ((const float4v*)in)[i];
  short4v o;
  o.x = (short)f2bf(v.x);
  o.y = (short)f2bf(v.y);
  o.z = (short)f2bf(v.z);
  o.w = (short)f2bf(v.w);
  ((short4v*)out)[i] = o;
}

// 128x128 tile, BK=32, 256 threads = 4 waves, each wave does 64x64 via
// 4x4 grid of v_mfma_f32_16x16x32_bf16. B^T layout (W rows contiguous in K).
__global__ __launch_bounds__(256, 2) void gemm_gates(
    const short* __restrict__ Xb,    // [16384,1024] bf16
    const short* __restrict__ Wb,    // [2048,1024] bf16 ([Wa;Wx])
    const float* __restrict__ xf,    // original fp32 x (for g = i*x)
    const float* __restrict__ ba,
    const float* __restrict__ bx,
    const float* __restrict__ lmbd,
    float* __restrict__ a_out,       // [16384,1024] a_t
    float* __restrict__ g_out)       // [16384,1024] i*x
{
  __shared__ __align__(16) short As[128 * 32];
  __shared__ __align__(16) short Bs[128 * 32];

  const int tile_m = blockIdx.x * 128;
  const int tile_n = blockIdx.y * 128;   // in [0,2048)
  const int tid  = threadIdx.x;
  const int wave = tid >> 6;
  const int lane = tid & 63;
  const int lrow = lane >> 2;            // 0..15 (staging row within 16-row chunk)
  const int lcol = (lane & 3) * 8;       // staging col (shorts)
  const int row16 = lane & 15;
  const int quad  = lane >> 4;
  const int wave_m = (wave & 1) * 64;
  const int wave_n = (wave >> 1) * 64;

  float4v acc[4][4] = {};

  const short* Ag = Xb + (size_t)(tile_m + wave * 16 + lrow) * K_DIM + lcol;
  const short* Bg = Wb + (size_t)(tile_n + wave * 16 + lrow) * K_DIM + lcol;
  char* AsB = (char*)As;
  char* BsB = (char*)Bs;

  for (int k0 = 0; k0 < K_DIM; k0 += 32) {
    // global->LDS async staging, 16B/lane; wave w fills rows [p*64+w*16, +16)
#pragma unroll
    for (int p = 0; p < 2; ++p) {
      __builtin_amdgcn_global_load_lds(
          (const __attribute__((address_space(1))) void*)(Ag + (size_t)p * 64 * K_DIM + k0),
          (__attribute__((address_space(3))) void*)(AsB + (p * 64 + wave * 16) * 64),
          16, 0, 0);
      __builtin_amdgcn_global_load_lds(
          (const __attribute__((address_space(1))) void*)(Bg + (size_t)p * 64 * K_DIM + k0),
          (__attribute__((address_space(3))) void*)(BsB + (p * 64 + wave * 16) * 64),
          16, 0, 0);
    }
    __syncthreads();

    short8 af[4], bfr[4];
#pragma unroll
    for (int i = 0; i < 4; ++i)
      af[i] = *(const short8*)&As[(wave_m + i * 16 + row16) * 32 + quad * 8];
#pragma unroll
    for (int i = 0; i < 4; ++i)
      bfr[i] = *(const short8*)&Bs[(wave_n + i * 16 + row16) * 32 + quad * 8];

#pragma unroll
    for (int mi = 0; mi < 4; ++mi)
#pragma unroll
      for (int ni = 0; ni < 4; ++ni)
        acc[mi][ni] = __builtin_amdgcn_mfma_f32_16x16x32_bf16(af[mi], bfr[ni], acc[mi][ni], 0, 0, 0);
    __syncthreads();
  }

  // Epilogue. C/D layout: col = lane&15, row = quad*4 + reg.
  const int base_row = tile_m + wave_m + quad * 4;
  if (tile_n < D_DIM) {
    // r-gate half: a_t = exp(8 * sigmoid(z) * log(sigmoid(lmbd)))
#pragma unroll
    for (int ni = 0; ni < 4; ++ni) {
      int ch = tile_n + wave_n + ni * 16 + row16;
      float bias = ba[ch];
      float la = -log1pf(expf(-lmbd[ch]));   // log(sigmoid(lmbd)) (lmbd>0, stable)
#pragma unroll
      for (int mi = 0; mi < 4; ++mi) {
        int r0 = base_row + mi * 16;
#pragma unroll
        for (int r = 0; r < 4; ++r) {
          float z = acc[mi][ni][r] + bias;
          float rg = 1.0f / (1.0f + expf(-z));
          a_out[(size_t)(r0 + r) * D_DIM + ch] = expf(8.0f * rg * la);
        }
      }
    }
  } else {
    // i-gate half: g = sigmoid(z) * x
#pragma unroll
    for (int ni = 0; ni < 4; ++ni) {
      int ch = tile_n - D_DIM + wave_n + ni * 16 + row16;
      float bias = bx[ch];
#pragma unroll
      for (int mi = 0; mi < 4; ++mi) {
        int r0 = base_row + mi * 16;
#pragma unroll
        for (int r = 0; r < 4; ++r) {
          float z = acc[mi][ni][r] + bias;
          float ig = 1.0f / (1.0f + expf(-z));
          g_out[(size_t)(r0 + r) * D_DIM + ch] = ig * xf[(size_t)(r0 + r) * D_DIM + ch];
        }
      }
    }
  }
}

// Phase 1: per-chunk composition (P = prod a, Q = chunk-local scan from 0).
// grid (D/256=4, NC=32, B=4), 256 threads.
__global__ void scan_phase1(const float* __restrict__ a, const float* __restrict__ g,
                            float* __restrict__ P, float* __restrict__ Q) {
  int d = blockIdx.x * 256 + threadIdx.x;
  int c = blockIdx.y;
  int b = blockIdx.z;
  const size_t base = ((size_t)(b * L_DIM + c * CL)) * D_DIM + d;
  float Pv = 1.0f, Qv = 0.0f;
#pragma unroll 4
  for (int t = 0; t < CL; ++t) {
    float at = a[base + (size_t)t * D_DIM];
    float gv = g[base + (size_t)t * D_DIM];
    float bt = sqrtf(fmaxf(1.0f - at * at, 0.0f)) * gv;
    Qv = fmaf(at, Qv, bt);
    Pv *= at;
  }
  int idx = (b * NC + c) * D_DIM + d;
  P[idx] = Pv;
  Q[idx] = Qv;
}

// Phase 2: prefix over the NC chunks per channel. 4096 threads.
__global__ void scan_phase2(const float* __restrict__ P, const float* __restrict__ Q,
                            float* __restrict__ Hin) {
  int tid = blockIdx.x * 256 + threadIdx.x;   // 0..4095
  int b = tid >> 10;
  int d = tid & 1023;
  float H = 0.0f;
#pragma unroll
  for (int c = 0; c < NC; ++c) {
    int idx = (b * NC + c) * D_DIM + d;
    Hin[idx] = H;                 // h entering chunk c
    H = fmaf(P[idx], H, Q[idx]);
  }
}

// Phase 3: replay each chunk from its correct incoming h, write y.
__global__ void scan_phase3(const float* __restrict__ a, const float* __restrict__ g,
                            const float* __restrict__ Hin, float* __restrict__ y) {
  int d = blockIdx.x * 256 + threadIdx.x;
  int c = blockIdx.y;
  int b = blockIdx.z;
  const size_t base = ((size_t)(b * L_DIM + c * CL)) * D_DIM + d;
  float h = Hin[(b * NC + c) * D_DIM + d];
#pragma unroll 4
  for (int t = 0; t < CL; ++t) {
    float at = a[base + (size_t)t * D_DIM];
    float gv = g[base + (size_t)t * D_DIM];
    float bt = sqrtf(fmaxf(1.0f - at * at, 0.0f)) * gv;
    h = fmaf(at, h, bt);
    y[base + (size_t)t * D_DIM] = h;
  }
}

extern "C" void kernel_launch(void* const* d_in, const int* in_sizes, int n_in,
                              void* d_out, int out_size, void* d_ws, size_t ws_size,
                              hipStream_t stream) {
  const float* x    = (const float*)d_in[0];   // [4,4096,1024]
  const float* Wa   = (const float*)d_in[1];   // [1024,1024]
  const float* Wx   = (const float*)d_in[2];
  const float* ba   = (const float*)d_in[3];
  const float* bx   = (const float*)d_in[4];
  const float* lmbd = (const float*)d_in[5];
  float* y = (float*)d_out;                    // [4,4096,1024] fp32

  // Workspace layout (~166 MiB):
  char* ws = (char*)d_ws;
  short* Xb    = (short*)ws;                          // 32 MiB  bf16 x
  short* Wb    = (short*)(ws + 33554432);             //  4 MiB  bf16 [Wa;Wx]
  float* a_buf = (float*)(ws + 37748736);             // 64 MiB  a_t
  float* g_buf = (float*)(ws + 104857600);            // 64 MiB  i*x
  float* P     = (float*)(ws + 171966464);            // 512 KiB
  float* Q     = (float*)(ws + 172490752);            // 512 KiB
  float* Hin   = (float*)(ws + 173015040);            // 512 KiB

  // fp32 -> bf16 converts
  cvt_bf16<<<16384, 256, 0, stream>>>(x,  Xb, M_DIM * K_DIM / 4);
  cvt_bf16<<<1024,  256, 0, stream>>>(Wa, Wb, D_DIM * D_DIM / 4);
  cvt_bf16<<<1024,  256, 0, stream>>>(Wx, Wb + (size_t)D_DIM * D_DIM, D_DIM * D_DIM / 4);

  // fused dual GEMM + gate epilogue
  dim3 gg(M_DIM / 128, N_DIM / 128);   // (128, 16)
  gemm_gates<<<gg, 256, 0, stream>>>(Xb, Wb, x, ba, bx, lmbd, a_buf, g_buf);

  // chunked scan
  dim3 sg(D_DIM / 256, NC, B_DIM);     // (4, 32, 4)
  scan_phase1<<<sg, 256, 0, stream>>>(a_buf, g_buf, P, Q);
  scan_phase2<<<16, 256, 0, stream>>>(P, Q, Hin);
  scan_phase3<<<sg, 256, 0, stream>>>(a_buf, g_buf, Hin, y);
}